// Round 8
// baseline (255.789 us; speedup 1.0000x reference)
//
#include <hip/hip_runtime.h>
#include <math.h>

#define NMOL  1024
#define N     128          // atoms per molecule (Schur-reduced SPD system size)
#define NELEM 10
#define BLOCK 256
#define PW    8            // panel width
#define NPAN  16           // 128 / 8
#define PSTR  12           // panel-column buffer row stride (floats)
#define USTR  132          // U-panel row stride (cols 0..129: 128=rhsY, 129=rhsZ)

typedef __attribute__((ext_vector_type(4))) float f4;

// wave w (=tid>>6) owns column chunks [8w, 8w+8) (32 cols).
// lane l owns rows r0=2l, r1=2l+1. Local chunks 0,1 (global 8w,8w+1) live in
// LDS Aex (slots: 0=(r0,c0) 1=(r0,c1) 2=(r1,c0) 3=(r1,c1)); local chunks 2..7
// live in registers Ar0[6]/Ar1[6] (index = c-2). This caps register demand
// under the 128-VGPR budget of 4 blocks/CU (R6/R7 spilled at 64 data f4).

__global__ __launch_bounds__(BLOCK, 4) void ceq_solve_kernel(
    const float* __restrict__ eneg,
    const float* __restrict__ positions,
    const float* __restrict__ node_attrs,
    const float* __restrict__ hardness,
    const float* __restrict__ total_charge,
    const int*   __restrict__ atomic_numbers,
    float* __restrict__ out)
{
    __shared__ __align__(16) f4    Aex[4][BLOCK];      // 16 KB thread-private overflow
    __shared__ __align__(16) float P[N * PSTR];        // staged panel columns (128 x 8)
    __shared__ __align__(16) float Up[PW * USTR];      // staged panel rows (8 x 130)
    __shared__ __align__(16) float Ublk[NPAN][PW][PW]; // per-panel 8x8 diag blocks
    __shared__ float rhsY[N], rhsZ[N];
    __shared__ float sxY[N], sxZ[N];
    __shared__ float px[N], py[N], pz[N], sg[N], dgv[N];
    __shared__ float lamS;

    const int m    = blockIdx.x;
    const int tid  = threadIdx.x;
    const int lane = tid & 63;
    const int wid  = tid >> 6;
    const int r0   = 2 * lane;
    const int r1   = r0 + 1;
    const int col0 = 32 * wid;
    const int base = m * N;

    // ---- per-atom precompute ----
    if (tid < N) {
        const int i = tid;
        const int Z = atomic_numbers[base + i];
        const float rad = 0.3f + 0.02f * (float)Z;
        sg[i] = rad * rad;
        const float* na = node_attrs + (size_t)(base + i) * NELEM;
        float best = na[0]; int bi = 0;
        #pragma unroll
        for (int e = 1; e < NELEM; ++e) {
            float v = na[e];
            if (v > best) { best = v; bi = e; }     // first-max = jnp.argmax
        }
        dgv[i] = hardness[bi] + 0.5641895835477563f / rad;  // h + 1/(sqrt(pi) r)
        const float* p = positions + (size_t)(base + i) * 3;
        px[i] = p[0]; py[i] = p[1]; pz[i] = p[2];
        rhsY[i] = -eneg[base + i];   // A y = b
        rhsZ[i] = 1.0f;              // A z = 1
    }
    __syncthreads();

    // ---- fill: rows r0,r1 x cols [col0, col0+32); chunks 0,1 -> Aex, 2..7 -> regs ----
    f4 Ar0[6], Ar1[6];
    {
        const float x0 = px[r0], y0 = py[r0], z0 = pz[r0], s0 = sg[r0], d0 = dgv[r0];
        #pragma unroll
        for (int c = 0; c < 8; ++c) {
            f4 v0;
            #pragma unroll
            for (int e = 0; e < 4; ++e) {
                const int j = col0 + 4 * c + e;
                float a0;
                if (j == r0) a0 = d0;
                else {
                    const float dx = x0 - px[j], dy = y0 - py[j], dz = z0 - pz[j];
                    const float d = sqrtf(dx * dx + dy * dy + dz * dz);
                    a0 = erff(d / (1.4142135623730951f * sqrtf(s0 + sg[j]))) / d;
                }
                ((float*)&v0)[e] = a0;
            }
            if (c < 2) Aex[c][tid] = v0; else Ar0[c - 2] = v0;
        }
        const float x1 = px[r1], y1 = py[r1], z1 = pz[r1], s1 = sg[r1], d1 = dgv[r1];
        #pragma unroll
        for (int c = 0; c < 8; ++c) {
            f4 v1;
            #pragma unroll
            for (int e = 0; e < 4; ++e) {
                const int j = col0 + 4 * c + e;
                float a1;
                if (j == r1) a1 = d1;
                else {
                    const float dx = x1 - px[j], dy = y1 - py[j], dz = z1 - pz[j];
                    const float d = sqrtf(dx * dx + dy * dy + dz * dz);
                    a1 = erff(d / (1.4142135623730951f * sqrtf(s1 + sg[j]))) / d;
                }
                ((float*)&v1)[e] = a1;
            }
            if (c < 2) Aex[2 + c][tid] = v1; else Ar1[c - 2] = v1;
        }
    }

    // ================= blocked unpivoted LU, A register+LDS resident =================
    for (int p = 0; p < NPAN; ++p) {
        const int k0   = PW * p;
        const int gclo = 2 * p + 2;          // first trailing chunk (global)
        const int wp   = p >> 2;             // wave holding panel columns

        // ---- stage panel columns (rows >= k0) -> P ----
        if (wid == wp && lane >= 4 * p) {
            f4 a00, a01, a10, a11;
            switch (p & 3) {
                case 0:  a00 = Aex[0][tid]; a01 = Aex[1][tid];
                         a10 = Aex[2][tid]; a11 = Aex[3][tid]; break;
                case 1:  a00 = Ar0[0]; a01 = Ar0[1]; a10 = Ar1[0]; a11 = Ar1[1]; break;
                case 2:  a00 = Ar0[2]; a01 = Ar0[3]; a10 = Ar1[2]; a11 = Ar1[3]; break;
                default: a00 = Ar0[4]; a01 = Ar0[5]; a10 = Ar1[4]; a11 = Ar1[5]; break;
            }
            *(f4*)&P[r0 * PSTR + 0] = a00; *(f4*)&P[r0 * PSTR + 4] = a01;
            *(f4*)&P[r1 * PSTR + 0] = a10; *(f4*)&P[r1 * PSTR + 4] = a11;
        }
        // ---- stage panel rows (trailing chunks of quarter) -> Up ----
        if (lane >= 4 * p && lane < 4 * p + 4) {
            const int u0 = r0 - k0, u1 = u0 + 1;
            #pragma unroll
            for (int c = 0; c < 2; ++c) {
                const int gc = 8 * wid + c;
                if (gc >= gclo) {
                    *(f4*)&Up[u0 * USTR + 4 * gc] = Aex[c][tid];
                    *(f4*)&Up[u1 * USTR + 4 * gc] = Aex[2 + c][tid];
                }
            }
            #pragma unroll
            for (int c = 2; c < 8; ++c) {
                const int gc = 8 * wid + c;
                if (gc >= gclo) {
                    *(f4*)&Up[u0 * USTR + 4 * gc] = Ar0[c - 2];
                    *(f4*)&Up[u1 * USTR + 4 * gc] = Ar1[c - 2];
                }
            }
        }
        if (tid < PW) {
            Up[tid * USTR + 128] = rhsY[k0 + tid];
            Up[tid * USTR + 129] = rhsZ[k0 + tid];
        }
        __syncthreads();

        // ---- panel factor: wave 0, rows k0..127, shuffle broadcasts ----
        if (wid == 0) {
            const int i0 = k0 + lane, i1 = i0 + 64;
            const bool v0 = i0 < N, v1 = i1 < N;
            float rg0[PW], rg1[PW];
            if (v0) {
                f4 a = *(const f4*)&P[i0 * PSTR], b = *(const f4*)&P[i0 * PSTR + 4];
                rg0[0]=a.x; rg0[1]=a.y; rg0[2]=a.z; rg0[3]=a.w;
                rg0[4]=b.x; rg0[5]=b.y; rg0[6]=b.z; rg0[7]=b.w;
            } else {
                #pragma unroll
                for (int j = 0; j < PW; ++j) rg0[j] = 0.0f;
            }
            if (v1) {
                f4 a = *(const f4*)&P[i1 * PSTR], b = *(const f4*)&P[i1 * PSTR + 4];
                rg1[0]=a.x; rg1[1]=a.y; rg1[2]=a.z; rg1[3]=a.w;
                rg1[4]=b.x; rg1[5]=b.y; rg1[6]=b.z; rg1[7]=b.w;
            } else {
                #pragma unroll
                for (int j = 0; j < PW; ++j) rg1[j] = 0.0f;
            }
            #pragma unroll
            for (int kk = 0; kk < PW; ++kk) {
                float pr[PW];
                #pragma unroll
                for (int j = kk; j < PW; ++j) pr[j] = __shfl(rg0[j], kk);
                const float dinv = 1.0f / pr[kk];
                if (v0 && i0 > k0 + kk) {
                    const float mult = rg0[kk] * dinv; rg0[kk] = mult;
                    #pragma unroll
                    for (int j = kk + 1; j < PW; ++j) rg0[j] -= mult * pr[j];
                }
                if (v1) {
                    const float mult = rg1[kk] * dinv; rg1[kk] = mult;
                    #pragma unroll
                    for (int j = kk + 1; j < PW; ++j) rg1[j] -= mult * pr[j];
                }
            }
            if (v0) {
                f4 a = { rg0[0], rg0[1], rg0[2], rg0[3] };
                f4 b = { rg0[4], rg0[5], rg0[6], rg0[7] };
                *(f4*)&P[i0 * PSTR] = a; *(f4*)&P[i0 * PSTR + 4] = b;
                if (lane < PW) { *(f4*)&Ublk[p][lane][0] = a; *(f4*)&Ublk[p][lane][4] = b; }
            }
            if (v1) {
                f4 a = { rg1[0], rg1[1], rg1[2], rg1[3] };
                f4 b = { rg1[4], rg1[5], rg1[6], rg1[7] };
                *(f4*)&P[i1 * PSTR] = a; *(f4*)&P[i1 * PSTR + 4] = b;
            }
        }
        __syncthreads();

        // ---- TRSM: L11^-1 over cols k0+8..127 plus rhs cols 128,129 ----
        const int ncols = 122 - k0;
        if (tid < ncols) {
            const int j = k0 + PW + tid;
            float u[PW];
            #pragma unroll
            for (int kk = 0; kk < PW; ++kk) u[kk] = Up[kk * USTR + j];
            #pragma unroll
            for (int kk = 1; kk < PW; ++kk) {
                float acc = u[kk];
                #pragma unroll
                for (int t = 0; t < kk; ++t) acc -= Ublk[p][kk][t] * u[t];
                u[kk] = acc;
            }
            #pragma unroll
            for (int kk = 0; kk < PW; ++kk) Up[kk * USTR + j] = u[kk];
        }
        __syncthreads();

        // ---- owner reload, rhs persist, GEMM (fused 2-row) ----
        if (lane >= 4 * p && lane < 4 * p + 4) {     // owners pull TRSM'd U back
            const int u0 = r0 - k0, u1 = u0 + 1;
            #pragma unroll
            for (int c = 0; c < 2; ++c) {
                const int gc = 8 * wid + c;
                if (gc >= gclo) {
                    Aex[c][tid]     = *(const f4*)&Up[u0 * USTR + 4 * gc];
                    Aex[2 + c][tid] = *(const f4*)&Up[u1 * USTR + 4 * gc];
                }
            }
            #pragma unroll
            for (int c = 2; c < 8; ++c) {
                const int gc = 8 * wid + c;
                if (gc >= gclo) {
                    Ar0[c - 2] = *(const f4*)&Up[u0 * USTR + 4 * gc];
                    Ar1[c - 2] = *(const f4*)&Up[u1 * USTR + 4 * gc];
                }
            }
        }
        if (tid < PW) {                               // persist forward-solved rhs rows
            rhsY[k0 + tid] = Up[tid * USTR + 128];
            rhsZ[k0 + tid] = Up[tid * USTR + 129];
        }
        const bool hasmat = (8 * wid + 7) >= gclo;
        if (lane >= 4 * p + 4) {                      // rows >= k0+8
            float lA0[PW], lA1[PW];
            {
                f4 a = *(const f4*)&P[r0 * PSTR], b = *(const f4*)&P[r0 * PSTR + 4];
                lA0[0]=a.x; lA0[1]=a.y; lA0[2]=a.z; lA0[3]=a.w;
                lA0[4]=b.x; lA0[5]=b.y; lA0[6]=b.z; lA0[7]=b.w;
                f4 c2 = *(const f4*)&P[r1 * PSTR], d2 = *(const f4*)&P[r1 * PSTR + 4];
                lA1[0]=c2.x; lA1[1]=c2.y; lA1[2]=c2.z; lA1[3]=c2.w;
                lA1[4]=d2.x; lA1[5]=d2.y; lA1[6]=d2.z; lA1[7]=d2.w;
            }
            if (hasmat) {
                #pragma unroll
                for (int c = 0; c < 2; ++c) {          // LDS-resident chunks
                    const int gc = 8 * wid + c;
                    if (gc >= gclo) {
                        f4 acc0 = Aex[c][tid], acc1 = Aex[2 + c][tid];
                        #pragma unroll
                        for (int u = 0; u < PW; ++u) {
                            const f4 uv = *(const f4*)&Up[u * USTR + 4 * gc];
                            acc0 -= uv * lA0[u];
                            acc1 -= uv * lA1[u];
                        }
                        Aex[c][tid] = acc0; Aex[2 + c][tid] = acc1;
                    }
                }
                #pragma unroll
                for (int c = 2; c < 8; ++c) {          // register chunks
                    const int gc = 8 * wid + c;
                    if (gc >= gclo) {
                        f4 acc0 = Ar0[c - 2], acc1 = Ar1[c - 2];
                        #pragma unroll
                        for (int u = 0; u < PW; ++u) {
                            const f4 uv = *(const f4*)&Up[u * USTR + 4 * gc];
                            acc0 -= uv * lA0[u];
                            acc1 -= uv * lA1[u];
                        }
                        Ar0[c - 2] = acc0; Ar1[c - 2] = acc1;
                    }
                }
            }
            if (wid == 0) {                           // rhs columns update
                float yy0 = rhsY[r0], yy1 = rhsY[r1];
                float zz0 = rhsZ[r0], zz1 = rhsZ[r1];
                #pragma unroll
                for (int u = 0; u < PW; ++u) {
                    const float uy = Up[u * USTR + 128];
                    const float uz = Up[u * USTR + 129];
                    yy0 -= lA0[u] * uy; yy1 -= lA1[u] * uy;
                    zz0 -= lA0[u] * uz; zz1 -= lA1[u] * uz;
                }
                rhsY[r0] = yy0; rhsY[r1] = yy1;
                rhsZ[r0] = zz0; rhsZ[r1] = zz1;
            }
        }
        __syncthreads();
    }

    // ================= blocked back substitution (both RHS) =================
    for (int pb = NPAN - 1; pb >= 0; --pb) {
        const int k0 = PW * pb;
        if (tid < 2) {                                // 8x8 upper-tri solve, Y and Z
            float* rhs = tid ? rhsZ : rhsY;
            float* sx  = tid ? sxZ  : sxY;
            float x[PW];
            #pragma unroll
            for (int kk = PW - 1; kk >= 0; --kk) {
                float acc = rhs[k0 + kk];
                #pragma unroll
                for (int jj = kk + 1; jj < PW; ++jj) acc -= Ublk[pb][kk][jj] * x[jj];
                x[kk] = acc / Ublk[pb][kk][kk];
                sx[k0 + kk] = x[kk];
            }
        }
        __syncthreads();
        if (wid == (pb >> 2) && lane < 4 * pb) {      // rank-8 back-update
            f4 a00, a01, a10, a11;
            switch (pb & 3) {
                case 0:  a00 = Aex[0][tid]; a01 = Aex[1][tid];
                         a10 = Aex[2][tid]; a11 = Aex[3][tid]; break;
                case 1:  a00 = Ar0[0]; a01 = Ar0[1]; a10 = Ar1[0]; a11 = Ar1[1]; break;
                case 2:  a00 = Ar0[2]; a01 = Ar0[3]; a10 = Ar1[2]; a11 = Ar1[3]; break;
                default: a00 = Ar0[4]; a01 = Ar0[5]; a10 = Ar1[4]; a11 = Ar1[5]; break;
            }
            float yy0 = rhsY[r0], yy1 = rhsY[r1];
            float zz0 = rhsZ[r0], zz1 = rhsZ[r1];
            yy0 -= a00.x*sxY[k0]   + a00.y*sxY[k0+1] + a00.z*sxY[k0+2] + a00.w*sxY[k0+3]
                 + a01.x*sxY[k0+4] + a01.y*sxY[k0+5] + a01.z*sxY[k0+6] + a01.w*sxY[k0+7];
            yy1 -= a10.x*sxY[k0]   + a10.y*sxY[k0+1] + a10.z*sxY[k0+2] + a10.w*sxY[k0+3]
                 + a11.x*sxY[k0+4] + a11.y*sxY[k0+5] + a11.z*sxY[k0+6] + a11.w*sxY[k0+7];
            zz0 -= a00.x*sxZ[k0]   + a00.y*sxZ[k0+1] + a00.z*sxZ[k0+2] + a00.w*sxZ[k0+3]
                 + a01.x*sxZ[k0+4] + a01.y*sxZ[k0+5] + a01.z*sxZ[k0+6] + a01.w*sxZ[k0+7];
            zz1 -= a10.x*sxZ[k0]   + a10.y*sxZ[k0+1] + a10.z*sxZ[k0+2] + a10.w*sxZ[k0+3]
                 + a11.x*sxZ[k0+4] + a11.y*sxZ[k0+5] + a11.z*sxZ[k0+6] + a11.w*sxZ[k0+7];
            rhsY[r0] = yy0; rhsY[r1] = yy1;
            rhsZ[r0] = zz0; rhsZ[r1] = zz1;
        }
        __syncthreads();
    }

    // ---- Schur closure: lambda = (1'y - Q)/(1'z - 1); q = y - lambda z ----
    if (wid == 0) {
        float vY = sxY[lane] + sxY[lane + 64];
        float vZ = sxZ[lane] + sxZ[lane + 64];
        #pragma unroll
        for (int off = 32; off; off >>= 1) {
            vY += __shfl_xor(vY, off);
            vZ += __shfl_xor(vZ, off);
        }
        if (lane == 0) lamS = (vY - total_charge[m]) / (vZ - 1.0f);
    }
    __syncthreads();
    if (tid < N) out[base + tid] = sxY[tid] - lamS * sxZ[tid];
}

extern "C" void kernel_launch(void* const* d_in, const int* in_sizes, int n_in,
                              void* d_out, int out_size, void* d_ws, size_t ws_size,
                              hipStream_t stream) {
    const float* eneg           = (const float*)d_in[0];
    const float* positions      = (const float*)d_in[1];
    const float* node_attrs     = (const float*)d_in[2];
    const float* hardness       = (const float*)d_in[3];
    const float* total_charge   = (const float*)d_in[4];
    // d_in[5] = batch (unused: equal-sized sorted molecules)
    const int*   atomic_numbers = (const int*)d_in[6];
    float* out = (float*)d_out;

    ceq_solve_kernel<<<NMOL, BLOCK, 0, stream>>>(
        eneg, positions, node_attrs, hardness, total_charge, atomic_numbers, out);
}

// Round 9
// 226.254 us; speedup vs baseline: 1.1305x; 1.1305x over previous
//
#include <hip/hip_runtime.h>
#include <math.h>

#define NMOL  1024
#define N     128          // atoms per molecule (Schur-reduced SPD system size)
#define NELEM 10
#define BLOCK 256          // 2 molecules per block: waves 0,1 = mol0; waves 2,3 = mol1
#define PW    8            // panel width
#define NPAN  16           // 128 / 8
#define PSTR  12           // panel-column buffer row stride (floats)
#define USTR  132          // U-panel row stride (cols 0..129: 128=rhsY, 129=rhsZ)

typedef __attribute__((ext_vector_type(4))) float f4;

// Per molecule: wave wv (=wid&1) owns chunks [16wv, 16wv+16) (64 cols).
// lane owns rows r0=2*lane, r1=r0+1: Ar0[16], Ar1[16] f4 (128 VGPRs data).
// __launch_bounds__(256,2): 2 blocks/CU -> 512 blocks all resident in ONE round;
// VGPR budget ~256 so the RA never spills (R6-R8 spilled at the (256,4) 64-reg clamp).

__global__ __launch_bounds__(BLOCK, 2) void ceq_solve_kernel(
    const float* __restrict__ eneg,
    const float* __restrict__ positions,
    const float* __restrict__ node_attrs,
    const float* __restrict__ hardness,
    const float* __restrict__ total_charge,
    const int*   __restrict__ atomic_numbers,
    float* __restrict__ out)
{
    __shared__ __align__(16) float P[2][N * PSTR];         // staged panel columns
    __shared__ __align__(16) float Up[2][PW * USTR];       // staged panel rows
    __shared__ __align__(16) float Ublk[2][NPAN][PW][PW];  // 8x8 diag blocks
    __shared__ float rhsY[2][N], rhsZ[2][N];
    __shared__ float sxY[2][N], sxZ[2][N];
    __shared__ float px[2][N], py[2][N], pz[2][N], sg[2][N], dgv[2][N];
    __shared__ float lamS[2];

    const int tid  = threadIdx.x;
    const int lane = tid & 63;
    const int wid  = tid >> 6;
    const int g    = tid >> 7;        // molecule within block (== wid>>1)
    const int wv   = wid & 1;         // wave within molecule
    const int gt   = tid & 127;       // thread within molecule
    const int r0   = 2 * lane;
    const int r1   = r0 + 1;
    const int col0 = 64 * wv;
    const int mol  = 2 * blockIdx.x + g;
    const int base = mol * N;

    // ---- per-atom precompute (thread gt loads atom gt of its molecule) ----
    {
        const int i = gt;
        const int Z = atomic_numbers[base + i];
        const float rad = 0.3f + 0.02f * (float)Z;
        sg[g][i] = rad * rad;
        const float* na = node_attrs + (size_t)(base + i) * NELEM;
        float best = na[0]; int bi = 0;
        #pragma unroll
        for (int e = 1; e < NELEM; ++e) {
            float v = na[e];
            if (v > best) { best = v; bi = e; }     // first-max = jnp.argmax
        }
        dgv[g][i] = hardness[bi] + 0.5641895835477563f / rad;  // h + 1/(sqrt(pi) r)
        const float* p = positions + (size_t)(base + i) * 3;
        px[g][i] = p[0]; py[g][i] = p[1]; pz[g][i] = p[2];
        rhsY[g][i] = -eneg[base + i];   // A y = b
        rhsZ[g][i] = 1.0f;              // A z = 1
    }
    __syncthreads();

    // ---- fill register tiles: rows r0,r1 x cols [col0, col0+64) ----
    f4 Ar0[16], Ar1[16];
    {
        const float x0 = px[g][r0], y0 = py[g][r0], z0 = pz[g][r0];
        const float s0 = sg[g][r0], d0 = dgv[g][r0];
        #pragma unroll
        for (int c = 0; c < 16; ++c) {
            f4 v0;
            #pragma unroll
            for (int e = 0; e < 4; ++e) {
                const int j = col0 + 4 * c + e;
                float a0;
                if (j == r0) a0 = d0;
                else {
                    const float dx = x0 - px[g][j], dy = y0 - py[g][j], dz = z0 - pz[g][j];
                    const float d = sqrtf(dx * dx + dy * dy + dz * dz);
                    a0 = erff(d / (1.4142135623730951f * sqrtf(s0 + sg[g][j]))) / d;
                }
                ((float*)&v0)[e] = a0;
            }
            Ar0[c] = v0;
        }
        const float x1 = px[g][r1], y1 = py[g][r1], z1 = pz[g][r1];
        const float s1 = sg[g][r1], d1 = dgv[g][r1];
        #pragma unroll
        for (int c = 0; c < 16; ++c) {
            f4 v1;
            #pragma unroll
            for (int e = 0; e < 4; ++e) {
                const int j = col0 + 4 * c + e;
                float a1;
                if (j == r1) a1 = d1;
                else {
                    const float dx = x1 - px[g][j], dy = y1 - py[g][j], dz = z1 - pz[g][j];
                    const float d = sqrtf(dx * dx + dy * dy + dz * dz);
                    a1 = erff(d / (1.4142135623730951f * sqrtf(s1 + sg[g][j]))) / d;
                }
                ((float*)&v1)[e] = a1;
            }
            Ar1[c] = v1;
        }
    }

    // ================= blocked unpivoted LU, A register-resident =================
    for (int p = 0; p < NPAN; ++p) {
        const int k0   = PW * p;
        const int gclo = 2 * p + 2;          // first trailing chunk (global)
        const int q    = p & 7;              // local chunk pair 2q,2q+1 in owner wave

        // ---- stage panel columns (rows >= k0) -> P[g] ----
        if (wv == (p >> 3) && lane >= 4 * p) {
            f4 a00, a01, a10, a11;
            switch (q) {
                case 0:  a00 = Ar0[0];  a01 = Ar0[1];  a10 = Ar1[0];  a11 = Ar1[1];  break;
                case 1:  a00 = Ar0[2];  a01 = Ar0[3];  a10 = Ar1[2];  a11 = Ar1[3];  break;
                case 2:  a00 = Ar0[4];  a01 = Ar0[5];  a10 = Ar1[4];  a11 = Ar1[5];  break;
                case 3:  a00 = Ar0[6];  a01 = Ar0[7];  a10 = Ar1[6];  a11 = Ar1[7];  break;
                case 4:  a00 = Ar0[8];  a01 = Ar0[9];  a10 = Ar1[8];  a11 = Ar1[9];  break;
                case 5:  a00 = Ar0[10]; a01 = Ar0[11]; a10 = Ar1[10]; a11 = Ar1[11]; break;
                case 6:  a00 = Ar0[12]; a01 = Ar0[13]; a10 = Ar1[12]; a11 = Ar1[13]; break;
                default: a00 = Ar0[14]; a01 = Ar0[15]; a10 = Ar1[14]; a11 = Ar1[15]; break;
            }
            *(f4*)&P[g][r0 * PSTR + 0] = a00; *(f4*)&P[g][r0 * PSTR + 4] = a01;
            *(f4*)&P[g][r1 * PSTR + 0] = a10; *(f4*)&P[g][r1 * PSTR + 4] = a11;
        }
        // ---- stage panel rows (trailing chunks of this wave's range) -> Up[g] ----
        if (lane >= 4 * p && lane < 4 * p + 4) {
            const int u0 = r0 - k0, u1 = u0 + 1;
            #pragma unroll
            for (int c = 0; c < 16; ++c) {
                const int gc = 16 * wv + c;
                if (gc >= gclo) {
                    *(f4*)&Up[g][u0 * USTR + 4 * gc] = Ar0[c];
                    *(f4*)&Up[g][u1 * USTR + 4 * gc] = Ar1[c];
                }
            }
        }
        if (gt < PW) {
            Up[g][gt * USTR + 128] = rhsY[g][k0 + gt];
            Up[g][gt * USTR + 129] = rhsZ[g][k0 + gt];
        }
        __syncthreads();

        // ---- panel factor: wave wv==0 of each molecule, shuffle broadcasts ----
        if (wv == 0) {
            const int i0 = k0 + lane, i1 = i0 + 64;
            const bool v0 = i0 < N, v1 = i1 < N;
            float rg0[PW], rg1[PW];
            if (v0) {
                f4 a = *(const f4*)&P[g][i0 * PSTR], b = *(const f4*)&P[g][i0 * PSTR + 4];
                rg0[0]=a.x; rg0[1]=a.y; rg0[2]=a.z; rg0[3]=a.w;
                rg0[4]=b.x; rg0[5]=b.y; rg0[6]=b.z; rg0[7]=b.w;
            } else {
                #pragma unroll
                for (int j = 0; j < PW; ++j) rg0[j] = 0.0f;
            }
            if (v1) {
                f4 a = *(const f4*)&P[g][i1 * PSTR], b = *(const f4*)&P[g][i1 * PSTR + 4];
                rg1[0]=a.x; rg1[1]=a.y; rg1[2]=a.z; rg1[3]=a.w;
                rg1[4]=b.x; rg1[5]=b.y; rg1[6]=b.z; rg1[7]=b.w;
            } else {
                #pragma unroll
                for (int j = 0; j < PW; ++j) rg1[j] = 0.0f;
            }
            #pragma unroll
            for (int kk = 0; kk < PW; ++kk) {
                float pr[PW];
                #pragma unroll
                for (int j = kk; j < PW; ++j) pr[j] = __shfl(rg0[j], kk);
                const float dinv = 1.0f / pr[kk];
                if (v0 && i0 > k0 + kk) {
                    const float mult = rg0[kk] * dinv; rg0[kk] = mult;
                    #pragma unroll
                    for (int j = kk + 1; j < PW; ++j) rg0[j] -= mult * pr[j];
                }
                if (v1) {
                    const float mult = rg1[kk] * dinv; rg1[kk] = mult;
                    #pragma unroll
                    for (int j = kk + 1; j < PW; ++j) rg1[j] -= mult * pr[j];
                }
            }
            if (v0) {
                f4 a = { rg0[0], rg0[1], rg0[2], rg0[3] };
                f4 b = { rg0[4], rg0[5], rg0[6], rg0[7] };
                *(f4*)&P[g][i0 * PSTR] = a; *(f4*)&P[g][i0 * PSTR + 4] = b;
                if (lane < PW) {
                    *(f4*)&Ublk[g][p][lane][0] = a; *(f4*)&Ublk[g][p][lane][4] = b;
                }
            }
            if (v1) {
                f4 a = { rg1[0], rg1[1], rg1[2], rg1[3] };
                f4 b = { rg1[4], rg1[5], rg1[6], rg1[7] };
                *(f4*)&P[g][i1 * PSTR] = a; *(f4*)&P[g][i1 * PSTR + 4] = b;
            }
        }
        __syncthreads();

        // ---- TRSM: L11^-1 over cols k0+8..127 plus rhs cols 128,129 ----
        const int ncols = 122 - k0;
        if (gt < ncols) {
            const int j = k0 + PW + gt;
            float u[PW];
            #pragma unroll
            for (int kk = 0; kk < PW; ++kk) u[kk] = Up[g][kk * USTR + j];
            #pragma unroll
            for (int kk = 1; kk < PW; ++kk) {
                float acc = u[kk];
                #pragma unroll
                for (int t = 0; t < kk; ++t) acc -= Ublk[g][p][kk][t] * u[t];
                u[kk] = acc;
            }
            #pragma unroll
            for (int kk = 0; kk < PW; ++kk) Up[g][kk * USTR + j] = u[kk];
        }
        __syncthreads();

        // ---- owner reload, rhs persist, GEMM ----
        if (lane >= 4 * p && lane < 4 * p + 4) {     // owners pull TRSM'd U back
            const int u0 = r0 - k0, u1 = u0 + 1;
            #pragma unroll
            for (int c = 0; c < 16; ++c) {
                const int gc = 16 * wv + c;
                if (gc >= gclo) {
                    Ar0[c] = *(const f4*)&Up[g][u0 * USTR + 4 * gc];
                    Ar1[c] = *(const f4*)&Up[g][u1 * USTR + 4 * gc];
                }
            }
        }
        if (gt < PW) {                                // persist forward-solved rhs rows
            rhsY[g][k0 + gt] = Up[g][gt * USTR + 128];
            rhsZ[g][k0 + gt] = Up[g][gt * USTR + 129];
        }
        const bool hasmat = (16 * wv + 15) >= gclo;
        if (lane >= 4 * p + 4) {                      // rows >= k0+8
            float lA0[PW], lA1[PW];
            if (hasmat || wv == 0) {
                f4 a = *(const f4*)&P[g][r0 * PSTR], b = *(const f4*)&P[g][r0 * PSTR + 4];
                lA0[0]=a.x; lA0[1]=a.y; lA0[2]=a.z; lA0[3]=a.w;
                lA0[4]=b.x; lA0[5]=b.y; lA0[6]=b.z; lA0[7]=b.w;
                f4 c2 = *(const f4*)&P[g][r1 * PSTR], d2 = *(const f4*)&P[g][r1 * PSTR + 4];
                lA1[0]=c2.x; lA1[1]=c2.y; lA1[2]=c2.z; lA1[3]=c2.w;
                lA1[4]=d2.x; lA1[5]=d2.y; lA1[6]=d2.z; lA1[7]=d2.w;
            }
            if (hasmat) {
                #pragma unroll
                for (int c = 0; c < 16; ++c) {
                    const int gc = 16 * wv + c;
                    if (gc >= gclo) {
                        f4 acc0 = Ar0[c], acc1 = Ar1[c];
                        #pragma unroll
                        for (int u = 0; u < PW; ++u) {
                            const f4 uv = *(const f4*)&Up[g][u * USTR + 4 * gc]; // broadcast
                            acc0 -= uv * lA0[u];
                            acc1 -= uv * lA1[u];
                        }
                        Ar0[c] = acc0; Ar1[c] = acc1;
                    }
                }
            }
            if (wv == 0) {                            // rhs columns update
                float yy0 = rhsY[g][r0], yy1 = rhsY[g][r1];
                float zz0 = rhsZ[g][r0], zz1 = rhsZ[g][r1];
                #pragma unroll
                for (int u = 0; u < PW; ++u) {
                    const float uy = Up[g][u * USTR + 128];
                    const float uz = Up[g][u * USTR + 129];
                    yy0 -= lA0[u] * uy; yy1 -= lA1[u] * uy;
                    zz0 -= lA0[u] * uz; zz1 -= lA1[u] * uz;
                }
                rhsY[g][r0] = yy0; rhsY[g][r1] = yy1;
                rhsZ[g][r0] = zz0; rhsZ[g][r1] = zz1;
            }
        }
        __syncthreads();
    }

    // ================= blocked back substitution (both RHS, both mols) =================
    for (int pb = NPAN - 1; pb >= 0; --pb) {
        const int k0 = PW * pb;
        if (tid < 4) {                                // 4 parallel 8x8 upper-tri solves
            const int gg = tid >> 1;
            float* rhs = (tid & 1) ? rhsZ[gg] : rhsY[gg];
            float* sx  = (tid & 1) ? sxZ[gg]  : sxY[gg];
            float x[PW];
            #pragma unroll
            for (int kk = PW - 1; kk >= 0; --kk) {
                float acc = rhs[k0 + kk];
                #pragma unroll
                for (int jj = kk + 1; jj < PW; ++jj) acc -= Ublk[gg][pb][kk][jj] * x[jj];
                x[kk] = acc / Ublk[gg][pb][kk][kk];
                sx[k0 + kk] = x[kk];
            }
        }
        __syncthreads();
        if (wv == (pb >> 3) && lane < 4 * pb) {       // rank-8 back-update from regs
            f4 a00, a01, a10, a11;
            switch (pb & 7) {
                case 0:  a00 = Ar0[0];  a01 = Ar0[1];  a10 = Ar1[0];  a11 = Ar1[1];  break;
                case 1:  a00 = Ar0[2];  a01 = Ar0[3];  a10 = Ar1[2];  a11 = Ar1[3];  break;
                case 2:  a00 = Ar0[4];  a01 = Ar0[5];  a10 = Ar1[4];  a11 = Ar1[5];  break;
                case 3:  a00 = Ar0[6];  a01 = Ar0[7];  a10 = Ar1[6];  a11 = Ar1[7];  break;
                case 4:  a00 = Ar0[8];  a01 = Ar0[9];  a10 = Ar1[8];  a11 = Ar1[9];  break;
                case 5:  a00 = Ar0[10]; a01 = Ar0[11]; a10 = Ar1[10]; a11 = Ar1[11]; break;
                case 6:  a00 = Ar0[12]; a01 = Ar0[13]; a10 = Ar1[12]; a11 = Ar1[13]; break;
                default: a00 = Ar0[14]; a01 = Ar0[15]; a10 = Ar1[14]; a11 = Ar1[15]; break;
            }
            float yy0 = rhsY[g][r0], yy1 = rhsY[g][r1];
            float zz0 = rhsZ[g][r0], zz1 = rhsZ[g][r1];
            yy0 -= a00.x*sxY[g][k0]   + a00.y*sxY[g][k0+1] + a00.z*sxY[g][k0+2] + a00.w*sxY[g][k0+3]
                 + a01.x*sxY[g][k0+4] + a01.y*sxY[g][k0+5] + a01.z*sxY[g][k0+6] + a01.w*sxY[g][k0+7];
            yy1 -= a10.x*sxY[g][k0]   + a10.y*sxY[g][k0+1] + a10.z*sxY[g][k0+2] + a10.w*sxY[g][k0+3]
                 + a11.x*sxY[g][k0+4] + a11.y*sxY[g][k0+5] + a11.z*sxY[g][k0+6] + a11.w*sxY[g][k0+7];
            zz0 -= a00.x*sxZ[g][k0]   + a00.y*sxZ[g][k0+1] + a00.z*sxZ[g][k0+2] + a00.w*sxZ[g][k0+3]
                 + a01.x*sxZ[g][k0+4] + a01.y*sxZ[g][k0+5] + a01.z*sxZ[g][k0+6] + a01.w*sxZ[g][k0+7];
            zz1 -= a10.x*sxZ[g][k0]   + a10.y*sxZ[g][k0+1] + a10.z*sxZ[g][k0+2] + a10.w*sxZ[g][k0+3]
                 + a11.x*sxZ[g][k0+4] + a11.y*sxZ[g][k0+5] + a11.z*sxZ[g][k0+6] + a11.w*sxZ[g][k0+7];
            rhsY[g][r0] = yy0; rhsY[g][r1] = yy1;
            rhsZ[g][r0] = zz0; rhsZ[g][r1] = zz1;
        }
        __syncthreads();
    }

    // ---- Schur closure: lambda = (1'y - Q)/(1'z - 1); q = y - lambda z ----
    if (wv == 0) {
        float vY = sxY[g][lane] + sxY[g][lane + 64];
        float vZ = sxZ[g][lane] + sxZ[g][lane + 64];
        #pragma unroll
        for (int off = 32; off; off >>= 1) {
            vY += __shfl_xor(vY, off);
            vZ += __shfl_xor(vZ, off);
        }
        if (lane == 0) lamS[g] = (vY - total_charge[mol]) / (vZ - 1.0f);
    }
    __syncthreads();
    out[base + gt] = sxY[g][gt] - lamS[g] * sxZ[g][gt];
}

extern "C" void kernel_launch(void* const* d_in, const int* in_sizes, int n_in,
                              void* d_out, int out_size, void* d_ws, size_t ws_size,
                              hipStream_t stream) {
    const float* eneg           = (const float*)d_in[0];
    const float* positions      = (const float*)d_in[1];
    const float* node_attrs     = (const float*)d_in[2];
    const float* hardness       = (const float*)d_in[3];
    const float* total_charge   = (const float*)d_in[4];
    // d_in[5] = batch (unused: equal-sized sorted molecules)
    const int*   atomic_numbers = (const int*)d_in[6];
    float* out = (float*)d_out;

    ceq_solve_kernel<<<NMOL / 2, BLOCK, 0, stream>>>(
        eneg, positions, node_attrs, hardness, total_charge, atomic_numbers, out);
}